// Round 5
// baseline (346.981 us; speedup 1.0000x reference)
//
#include <hip/hip_runtime.h>
#include <hip/hip_bf16.h>

// CrossAttention R11 = R10 + GEMM latency fixes (attn untouched).
//  - R10 counters: gemm128 MODE0 92us, MfmaUtil 7.2%, Occ 11%, HBM 12% --
//    latency-bound, not BW/MFMA. FETCH 67.8MB = 4x ideal (A re-fetched per XCD:
//    grid (x=n,y=m) => XCD=n%8 spreads same-A-panel blocks across all XCDs).
//    Staging reads 64B per 2KB-strided row => 16 half-line requests per gload.
//  - Fix 1: grid swap (x=m, y=n) => XCD=m%8: the 8-16 n-blocks sharing an
//    A-panel run concurrently on ONE XCD -> L2 MSHR-merged, A fetched ~once.
//  - Fix 2: BK=64 per iter as two BK=32 planes (verified addressing preserved):
//    adjacent half-line pairs merge to full lines, 2x compute per wait,
//    16 iters. 2 bufs x 32KB = 64KB, 2 blocks/CU. Two-barrier counted scheme:
//    compute -> lgkm(0)+bar -> stage(t+2) -> vmcnt(8)+bar (never drain to 0).
//  - attn: R10 structure (2 q-tiles/block, Q pre-scaled by 0.125*log2e).

typedef short bf16x8 __attribute__((ext_vector_type(8)));
typedef float f32x4 __attribute__((ext_vector_type(4)));

__device__ __forceinline__ short f2s(float f) {
    __hip_bfloat16 h = __float2bfloat16(f);
    return __builtin_bit_cast(short, h);
}

__device__ __forceinline__ f32x4 mfma16(bf16x8 a, bf16x8 b, f32x4 c) {
    return __builtin_amdgcn_mfma_f32_16x16x32_bf16(a, b, c, 0, 0, 0);
}

__device__ __forceinline__ void gload16(short* lds, const short* g) {
    __builtin_amdgcn_global_load_lds((const __attribute__((address_space(1))) void*)g,
                                     (__attribute__((address_space(3))) void*)lds,
                                     16, 0, 0);
}

// Barrier with guaranteed counter drain (prologue/epilogue + attn loop).
__device__ __forceinline__ void drain_barrier() {
    asm volatile("s_waitcnt vmcnt(0) lgkmcnt(0)" ::: "memory");
    __syncthreads();
}

__device__ __forceinline__ unsigned int fbits(float f) {
    return __builtin_bit_cast(unsigned int, f);
}

// ---------------- prep: fp32 -> bf16 for activations ----------------
__global__ __launch_bounds__(256) void conv_to_bf16(const float* __restrict__ x,
                                                    const float* __restrict__ ctx,
                                                    short* __restrict__ xb,
                                                    short* __restrict__ cb) {
    const size_t NV = 2097152;
    size_t i = (size_t)blockIdx.x * 256 + threadIdx.x;
    const float4* src = (i < NV) ? (const float4*)x : (const float4*)ctx;
    short* dst = (i < NV) ? xb : cb;
    size_t idx = (i < NV) ? i : i - NV;
    float4 v = src[idx];
    short4 o;
    o.x = f2s(v.x); o.y = f2s(v.y); o.z = f2s(v.z); o.w = f2s(v.w);
    ((short4*)dst)[idx] = o;
}

// ---------------- prep: W -> W^T bf16 (K+V halves contiguous in WkvT) ----------------
__global__ __launch_bounds__(256) void transpose_weights(
    const float* __restrict__ q_w, const float* __restrict__ kv_w,
    const float* __restrict__ proj_w,
    short* __restrict__ WqT, short* __restrict__ WkvT, short* __restrict__ WpT) {
    __shared__ float t[32][33];
    const float* src; short* dst; int ld, coff;
    switch (blockIdx.z) {
        case 0:  src = q_w;    dst = WqT;                 ld = 1024; coff = 0;    break;
        case 1:  src = kv_w;   dst = WkvT;                ld = 2048; coff = 0;    break;
        case 2:  src = kv_w;   dst = WkvT + 1024 * 1024;  ld = 2048; coff = 1024; break;
        default: src = proj_w; dst = WpT;                 ld = 1024; coff = 0;    break;
    }
    int n0 = blockIdx.x * 32, k0 = blockIdx.y * 32;
    int tx = threadIdx.x & 31, ty = threadIdx.x >> 5;
    #pragma unroll
    for (int j = 0; j < 32; j += 8)
        t[ty + j][tx] = src[(size_t)(k0 + ty + j) * ld + coff + n0 + tx];
    __syncthreads();
    #pragma unroll
    for (int j = 0; j < 32; j += 8)
        dst[(size_t)(n0 + ty + j) * 1024 + k0 + tx] = f2s(t[tx][ty + j]);
}

// ---------------- GEMM 128x128, K=1024, BK=64 (2 planes), 2-buffer counted ----------------
// grid: x = m-tile (XCD affinity: same-A-panel blocks co-located), y = n-tile.
// MODE 0: Q proj -> per-head LN -> RoPE -> *0.125*log2e -> Q[b,h,s,64] bf16
// MODE 1: KV proj (N=2048): n0<1024 -> K path (LN -> K[b,h,sc,64]); else V path
// MODE 2: out proj -> + bias -> fp32 out
template <int MODE>
__global__ __launch_bounds__(256, 2) void gemm128(
    const short* __restrict__ A,    // [8192][1024] bf16 row-major
    const short* __restrict__ Bt,   // [N][1024] bf16 (N-major, K contiguous)
    const float* __restrict__ ln_scale,
    const float* __restrict__ ln_bias,
    short* __restrict__ outB,
    short* __restrict__ outB2,
    float* __restrict__ outF,
    const float* __restrict__ bias_vec) {
    // 2 bufs x (A 2x[128][32] + B 2x[128][32]) = 32768 shorts (64KB);
    // epilogue overlay 128x132 (16896 shorts) fits inside.
    __shared__ short smem[32768];
    const int tid = threadIdx.x;
    const int w = tid >> 6, lane = tid & 63, quad = lane >> 4, l15 = lane & 15;
    const int wr = w & 1, wc = w >> 1;
    const int m0 = blockIdx.x * 128, n0 = blockIdx.y * 128;  // grid swapped

    const int srow = lane >> 2, slot = lane & 3;
    const int kslot = (slot ^ ((srow >> 1) & 3)) * 8;  // XOR swizzle: 2-way banks on read
    const short* Ag0 = A + (size_t)(m0 + w * 32 + srow) * 1024 + kslot;
    const short* Ag1 = Ag0 + (size_t)16 * 1024;
    const short* Bg0 = Bt + (size_t)(n0 + w * 32 + srow) * 1024 + kslot;
    const short* Bg1 = Bg0 + (size_t)16 * 1024;

    f32x4 acc[4][4];
    #pragma unroll
    for (int r = 0; r < 4; r++)
        #pragma unroll
        for (int c = 0; c < 4; c++) acc[r][c] = f32x4{0.f, 0.f, 0.f, 0.f};

    const int rsw = (l15 >> 1) & 3;
    const int rch = (quad ^ rsw) * 8;

    // stage one BK=64 tile (two BK=32 planes) into buffer at 'bufo'
    auto stage = [&](int bufo, int kb) {
        gload16(smem + bufo + w * 1024,               Ag0 + kb);
        gload16(smem + bufo + w * 1024 + 512,         Ag1 + kb);
        gload16(smem + bufo + 4096 + w * 1024,        Ag0 + kb + 32);
        gload16(smem + bufo + 4096 + w * 1024 + 512,  Ag1 + kb + 32);
        gload16(smem + bufo + 8192 + w * 1024,        Bg0 + kb);
        gload16(smem + bufo + 8192 + w * 1024 + 512,  Bg1 + kb);
        gload16(smem + bufo + 12288 + w * 1024,       Bg0 + kb + 32);
        gload16(smem + bufo + 12288 + w * 1024 + 512, Bg1 + kb + 32);
    };

    // prologue: tile0 -> buf0, tile1 -> buf1; wait tile0's 8 loads only.
    stage(0, 0);
    stage(16384, 64);
    asm volatile("s_waitcnt vmcnt(8)" ::: "memory");
    __builtin_amdgcn_s_barrier();

    #pragma unroll 1
    for (int t = 0; t < 16; t++) {
        const int curo = (t & 1) * 16384;
        #pragma unroll
        for (int ks = 0; ks < 2; ks++) {
            bf16x8 af[4], bfr[4];
            #pragma unroll
            for (int rt = 0; rt < 4; rt++)
                af[rt] = *(const bf16x8*)(smem + curo + ks * 4096 +
                                          (wr * 64 + rt * 16 + l15) * 32 + rch);
            #pragma unroll
            for (int ct = 0; ct < 4; ct++)
                bfr[ct] = *(const bf16x8*)(smem + curo + 8192 + ks * 4096 +
                                           (wc * 64 + ct * 16 + l15) * 32 + rch);
            #pragma unroll
            for (int rt = 0; rt < 4; rt++)
                #pragma unroll
                for (int ct = 0; ct < 4; ct++)
                    acc[rt][ct] = mfma16(af[rt], bfr[ct], acc[rt][ct]);
        }
        // all my LDS reads of buf[cur] retired; block-wide before overwrite
        asm volatile("s_waitcnt lgkmcnt(0)" ::: "memory");
        __builtin_amdgcn_s_barrier();
        if (t < 14) {
            stage(curo, (t + 2) * 64);  // overwrite just-freed buffer with t+2
            // oldest 8 (tile t+1) landed; tile t+2's 8 stay in flight
            asm volatile("s_waitcnt vmcnt(8) lgkmcnt(0)" ::: "memory");
        } else {
            asm volatile("s_waitcnt vmcnt(0) lgkmcnt(0)" ::: "memory");
        }
        __builtin_amdgcn_s_barrier();  // tile t+1 published to all waves
    }

    // epilogue: lane holds C[row = wr*64+rt*16+quad*4+i][col = wc*64+ct*16+l15]
    const bool vpath = (MODE == 1) && (n0 >= 1024);
    if constexpr (MODE == 0 || MODE == 1) {
        if (!vpath) {
            #pragma unroll
            for (int rt = 0; rt < 4; rt++) {
                #pragma unroll
                for (int i = 0; i < 4; i++) {
                    float s = acc[rt][0][i] + acc[rt][1][i] + acc[rt][2][i] + acc[rt][3][i];
                    float q = acc[rt][0][i] * acc[rt][0][i] + acc[rt][1][i] * acc[rt][1][i] +
                              acc[rt][2][i] * acc[rt][2][i] + acc[rt][3][i] * acc[rt][3][i];
                    #pragma unroll
                    for (int off = 1; off < 16; off <<= 1) {
                        s += __shfl_xor(s, off, 64);
                        q += __shfl_xor(q, off, 64);
                    }
                    float mu = s * (1.f / 64.f);
                    float var = q * (1.f / 64.f) - mu * mu;
                    float rs = rsqrtf(var + 1e-5f);
                    float vals[4];
                    #pragma unroll
                    for (int ct = 0; ct < 4; ct++) {
                        int hd = ct * 16 + l15;
                        vals[ct] = (acc[rt][ct][i] - mu) * rs * ln_scale[hd] + ln_bias[hd];
                    }
                    if constexpr (MODE == 0) {  // RoPE pairs (hd, hd+32) = (ct, ct+2)
                        int sp = (m0 + wr * 64 + rt * 16 + quad * 4 + i) & 2047;
                        #pragma unroll
                        for (int ct = 0; ct < 2; ct++) {
                            int hd1 = ct * 16 + l15;
                            float ang = (float)sp * exp2f((float)hd1 * (-13.287712379549449f / 32.f));
                            float sn, cs;
                            sincosf(ang, &sn, &cs);
                            float v1 = vals[ct], v2 = vals[ct + 2];
                            vals[ct]     = v1 * cs - v2 * sn;
                            vals[ct + 2] = v1 * sn + v2 * cs;
                        }
                        // fold softmax scale*log2e into Q: attn exp2 arg = raw dot
                        #pragma unroll
                        for (int ct = 0; ct < 4; ct++) vals[ct] *= 0.1803368801f;
                    }
                    #pragma unroll
                    for (int ct = 0; ct < 4; ct++) acc[rt][ct][i] = vals[ct];
                }
            }
            drain_barrier();
            short* Csm = smem;  // overlay: [128][132] bf16, +4 pad
            #pragma unroll
            for (int rt = 0; rt < 4; rt++)
                #pragma unroll
                for (int ct = 0; ct < 4; ct++)
                    #pragma unroll
                    for (int i = 0; i < 4; i++)
                        Csm[(wr * 64 + rt * 16 + quad * 4 + i) * 132 + wc * 64 + ct * 16 + l15] =
                            f2s(acc[rt][ct][i]);
            drain_barrier();
            #pragma unroll
            for (int it = 0; it < 8; it++) {
                int row = it * 16 + (tid >> 4);
                int chunk = tid & 15;
                bf16x8 v = *(const bf16x8*)(Csm + row * 132 + chunk * 8);
                int hh = ((n0 & 1023) >> 6) + (chunk >> 3);
                int m = m0 + row, b = m >> 11, sp = m & 2047;
                *(bf16x8*)(outB + ((size_t)(b * 16 + hh) * 2048 + sp) * 64 + (chunk & 7) * 8) = v;
            }
        } else {
            // V path: transposed store V^T[b,h,hd,sc]
            const int b = m0 >> 11, h = ((n0 - 1024) >> 6) + wc;
            const int sp = (m0 & 2047) + wr * 64 + quad * 4;
            #pragma unroll
            for (int rt = 0; rt < 4; rt++)
                #pragma unroll
                for (int ct = 0; ct < 4; ct++) {
                    short4 pk;
                    pk.x = f2s(acc[rt][ct][0]); pk.y = f2s(acc[rt][ct][1]);
                    pk.z = f2s(acc[rt][ct][2]); pk.w = f2s(acc[rt][ct][3]);
                    int hd = ct * 16 + l15;
                    *(short4*)(outB2 + ((size_t)(b * 16 + h) * 64 + hd) * 2048 + sp + rt * 16) = pk;
                }
        }
    } else {
        #pragma unroll
        for (int rt = 0; rt < 4; rt++)
            #pragma unroll
            for (int i = 0; i < 4; i++) {
                size_t m = m0 + wr * 64 + rt * 16 + quad * 4 + i;
                #pragma unroll
                for (int ct = 0; ct < 4; ct++) {
                    int n = n0 + wc * 64 + ct * 16 + l15;
                    outF[m * 1024 + n] = acc[rt][ct][i] + bias_vec[n];
                }
            }
    }
}

// ---------------- attention: 2 q-tiles per block, tail-free (R10) ----------------
// S^T = K.Q^T with Q pre-scaled by 0.125*log2e -> p = exp2(st) (row offset
// dropped; cancels in normalization). grid (64,8): block handles q-tiles
// {qt, qt+8}. LDS: K 2buf | V 2buf | P_A | P_B = 68KB -> 2 blocks/CU.
__global__ __launch_bounds__(256, 2) void attn_kernel(
    const short* __restrict__ Q,   // [64][2048][64]
    const short* __restrict__ K,   // [64][2048][64]
    const short* __restrict__ V,   // [64][64][2048]  (V^T)
    short* __restrict__ AO) {      // [8192][1024] bf16
    __shared__ short smem[8192 + 8192 + 2 * 4 * 32 * 72];
    const int tid = threadIdx.x;
    const int w = tid >> 6, lane = tid & 63, quad = lane >> 4, l15 = lane & 15;
    const int bh = blockIdx.x, qt = blockIdx.y;  // grid (64,8): head -> XCD = bh%8
    const short* Qb = Q + (size_t)bh * 2048 * 64;
    const short* Kb = K + (size_t)bh * 2048 * 64;
    const short* Vb = V + (size_t)bh * 64 * 2048;
    const int q0g[2] = {qt * 128 + w * 32, (qt + 8) * 128 + w * 32};

    const int srow = lane >> 2, slot = lane & 3;
    const int sw = (slot ^ ((srow >> 1) & 3)) * 8;
    const short* Kg = Kb + (size_t)(w * 16 + srow) * 64 + sw;
    const short* Vg = Vb + (size_t)(w * 16 + srow) * 2048 + sw;
    short* Kl0 = smem + w * 512;           // 16 rows/wave/plane
    short* Vl0 = smem + 8192 + w * 512;

    bf16x8 bq[2][2][2];  // [group][nt][ks]: Q as B-operand B[n=qrow][k=hd]
    #pragma unroll
    for (int g = 0; g < 2; g++)
        #pragma unroll
        for (int nt = 0; nt < 2; nt++)
            #pragma unroll
            for (int ks = 0; ks < 2; ks++)
                bq[g][nt][ks] =
                    *(const bf16x8*)(Qb + (size_t)(q0g[g] + nt * 16 + l15) * 64 + ks * 32 + quad * 8);

    f32x4 acco[2][4][2];  // [group][ct(hd)][nt(qrow)] O^T
    #pragma unroll
    for (int g = 0; g < 2; g++)
        #pragma unroll
        for (int ct = 0; ct < 4; ct++)
            #pragma unroll
            for (int nt = 0; nt < 2; nt++) acco[g][ct][nt] = f32x4{0.f, 0.f, 0.f, 0.f};
    float lsum[2][2] = {{0.f, 0.f}, {0.f, 0.f}};
    const int rsw = (l15 >> 1) & 3;
    const int rch = (quad ^ rsw) * 8;

    gload16(Kl0,        Kg);
    gload16(Kl0 + 2048, Kg + 32);
    gload16(Vl0,        Vg);
    gload16(Vl0 + 2048, Vg + 32);
    drain_barrier();

    #pragma unroll 1
    for (int t = 0; t < 32; t++) {
        const int cur = (t & 1) * 4096;
        if (t < 31) {
            const int nxt = 4096 - cur;
            const int sc = (t + 1) * 64;
            gload16(Kl0 + nxt,        Kg + sc * 64);
            gload16(Kl0 + nxt + 2048, Kg + sc * 64 + 32);
            gload16(Vl0 + nxt,        Vg + sc);
            gload16(Vl0 + nxt + 2048, Vg + sc + 32);
        }
        // ---- phase 1: K fragments, QK^T + exp2 + P stores for both groups ----
        bf16x8 ak[4][2];
        #pragma unroll
        for (int mt = 0; mt < 4; mt++)
            #pragma unroll
            for (int ks = 0; ks < 2; ks++)
                ak[mt][ks] = *(const bf16x8*)(smem + cur + ks * 2048 + (mt * 16 + l15) * 32 + rch);

        #pragma unroll
        for (int g = 0; g < 2; g++) {
            short* Pw = smem + 16384 + g * 9216 + w * 2304;
            #pragma unroll
            for (int mt = 0; mt < 4; mt++) {
                #pragma unroll
                for (int nt = 0; nt < 2; nt++) {
                    f32x4 st = f32x4{0.f, 0.f, 0.f, 0.f};
                    st = mfma16(ak[mt][0], bq[g][nt][0], st);
                    st = mfma16(ak[mt][1], bq[g][nt][1], st);
                    float e0 = __builtin_amdgcn_exp2f(st[0]);
                    float e1 = __builtin_amdgcn_exp2f(st[1]);
                    float e2 = __builtin_amdgcn_exp2f(st[2]);
                    float e3 = __builtin_amdgcn_exp2f(st[3]);
                    lsum[g][nt] += (e0 + e1) + (e2 + e3);
                    unsigned int p01 = __builtin_amdgcn_perm(fbits(e1), fbits(e0), 0x07060302u);
                    unsigned int p23 = __builtin_amdgcn_perm(fbits(e3), fbits(e2), 0x07060302u);
                    uint2 pw;
                    pw.x = p01; pw.y = p23;
                    *(uint2*)(Pw + (nt * 16 + l15) * 72 + mt * 16 + quad * 4) = pw;
                }
            }
        }
        // P written via uint2*, read via bf16x8*: fence pins program order
        // (wave-local LDS ops execute in issue order -> order == correctness).
        asm volatile("" ::: "memory");

        // ---- phase 2: V fragments, P reads + PV for both groups ----
        bf16x8 av[4][2];
        #pragma unroll
        for (int ct = 0; ct < 4; ct++)
            #pragma unroll
            for (int ks = 0; ks < 2; ks++)
                av[ct][ks] = *(const bf16x8*)(smem + 8192 + cur + ks * 2048 + (ct * 16 + l15) * 32 + rch);

        #pragma unroll
        for (int g = 0; g < 2; g++) {
            short* Pw = smem + 16384 + g * 9216 + w * 2304;
            bf16x8 bp[2][2];
            #pragma unroll
            for (int nt = 0; nt < 2; nt++)
                #pragma unroll
                for (int ks = 0; ks < 2; ks++)
                    bp[nt][ks] = *(const bf16x8*)(Pw + (nt * 16 + l15) * 72 + ks * 32 + quad * 8);
            #pragma unroll
            for (int ct = 0; ct < 4; ct++)
                #pragma unroll
                for (int nt = 0; nt < 2; nt++)
                    #pragma unroll
                    for (int ks = 0; ks < 2; ks++)
                        acco[g][ct][nt] = mfma16(av[ct][ks], bp[nt][ks], acco[g][ct][nt]);
        }
        drain_barrier();
    }

    #pragma unroll
    for (int g = 0; g < 2; g++)
        #pragma unroll
        for (int nt = 0; nt < 2; nt++) {
            lsum[g][nt] += __shfl_xor(lsum[g][nt], 16, 64);
            lsum[g][nt] += __shfl_xor(lsum[g][nt], 32, 64);
        }
    const int b = bh >> 4, h = bh & 15;
    #pragma unroll
    for (int g = 0; g < 2; g++)
        #pragma unroll
        for (int nt = 0; nt < 2; nt++) {
            float inv = 1.f / lsum[g][nt];
            int sq = q0g[g] + nt * 16 + l15;
            #pragma unroll
            for (int ct = 0; ct < 4; ct++) {
                short4 pk;
                pk.x = f2s(acco[g][ct][nt][0] * inv); pk.y = f2s(acco[g][ct][nt][1] * inv);
                pk.z = f2s(acco[g][ct][nt][2] * inv); pk.w = f2s(acco[g][ct][nt][3] * inv);
                *(short4*)(AO + ((size_t)b * 2048 + sq) * 1024 + h * 64 + ct * 16 + quad * 4) = pk;
            }
        }
}

extern "C" void kernel_launch(void* const* d_in, const int* in_sizes, int n_in,
                              void* d_out, int out_size, void* d_ws, size_t ws_size,
                              hipStream_t stream) {
    (void)in_sizes; (void)n_in; (void)out_size; (void)ws_size;
    const float* x      = (const float*)d_in[0];
    const float* ctx    = (const float*)d_in[1];
    const float* q_w    = (const float*)d_in[2];
    const float* kv_w   = (const float*)d_in[3];
    const float* qn_s   = (const float*)d_in[4];
    const float* qn_b   = (const float*)d_in[5];
    const float* kn_s   = (const float*)d_in[6];
    const float* kn_b   = (const float*)d_in[7];
    const float* proj_w = (const float*)d_in[8];
    const float* proj_b = (const float*)d_in[9];
    float* out = (float*)d_out;

    char* ws = (char*)d_ws;
    const size_t MB = 1024 * 1024;
    short* xb   = (short*)(ws + 0 * MB);
    short* cb   = (short*)(ws + 16 * MB);
    short* Qb   = (short*)(ws + 32 * MB);   // [64][2048][64] post LN+RoPE+scale
    short* Kb   = (short*)(ws + 48 * MB);   // [64][2048][64] post LN
    short* Vt   = (short*)(ws + 64 * MB);   // [64][64][2048]
    short* AO   = (short*)(ws + 80 * MB);   // [8192][1024]
    short* WqT  = (short*)(ws + 96 * MB);   // 2MB
    short* WkvT = (short*)(ws + 98 * MB);   // 4MB  [2048][1024]
    short* WpT  = (short*)(ws + 102 * MB);  // 2MB

    conv_to_bf16<<<16384, 256, 0, stream>>>(x, ctx, xb, cb);
    transpose_weights<<<dim3(32, 32, 4), 256, 0, stream>>>(q_w, kv_w, proj_w, WqT, WkvT, WpT);
    gemm128<0><<<dim3(64, 8), 256, 0, stream>>>(xb, WqT, qn_s, qn_b, Qb, nullptr, nullptr, nullptr);
    gemm128<1><<<dim3(64, 16), 256, 0, stream>>>(cb, WkvT, kn_s, kn_b, Kb, Vt, nullptr, nullptr);
    attn_kernel<<<dim3(64, 8), 256, 0, stream>>>(Qb, Kb, Vt, AO);
    gemm128<2><<<dim3(64, 8), 256, 0, stream>>>(AO, WpT, nullptr, nullptr, nullptr, nullptr, out, proj_b);
}

// Round 6
// 324.215 us; speedup vs baseline: 1.0702x; 1.0702x over previous
//
#include <hip/hip_runtime.h>
#include <hip/hip_bf16.h>

// CrossAttention R12 = R10 GEMM structure + grid-axis swap ONLY (attn untouched).
//  - R11 post-mortem: bundled {grid swap, BK=64 2-buf, 8 waves/CU} -> mode0
//    improved (<88us) but total regressed 329.6->347: the occupancy drop
//    (12->8 waves/CU) + 2 barriers/iter cost more on modes 1/2 than request
//    merging gained. Unbundled: back to R10's 3-buffer BK=32 counted pipeline
//    (48KB, 12 waves/CU, one barrier/iter).
//  - Kept from R11: grid (x=m-tile, y=n-tile) => XCD = m%8. The 8-16 n-blocks
//    sharing an A-row-panel are co-resident on ONE XCD -> L2 MSHR merge, A
//    fetched ~once (R10 mode0 FETCH 67.8MB vs ~19 ideal; mode1 worse).
//  - attn: R10 structure (2 q-tiles/block, Q pre-scaled by 0.125*log2e), 88us.

typedef short bf16x8 __attribute__((ext_vector_type(8)));
typedef float f32x4 __attribute__((ext_vector_type(4)));

__device__ __forceinline__ short f2s(float f) {
    __hip_bfloat16 h = __float2bfloat16(f);
    return __builtin_bit_cast(short, h);
}

__device__ __forceinline__ f32x4 mfma16(bf16x8 a, bf16x8 b, f32x4 c) {
    return __builtin_amdgcn_mfma_f32_16x16x32_bf16(a, b, c, 0, 0, 0);
}

__device__ __forceinline__ void gload16(short* lds, const short* g) {
    __builtin_amdgcn_global_load_lds((const __attribute__((address_space(1))) void*)g,
                                     (__attribute__((address_space(3))) void*)lds,
                                     16, 0, 0);
}

// Barrier with guaranteed counter drain (correctness of single-barrier dbuf).
__device__ __forceinline__ void drain_barrier() {
    asm volatile("s_waitcnt vmcnt(0) lgkmcnt(0)" ::: "memory");
    __syncthreads();
}

__device__ __forceinline__ unsigned int fbits(float f) {
    return __builtin_bit_cast(unsigned int, f);
}

// ---------------- prep: fp32 -> bf16 for activations ----------------
__global__ __launch_bounds__(256) void conv_to_bf16(const float* __restrict__ x,
                                                    const float* __restrict__ ctx,
                                                    short* __restrict__ xb,
                                                    short* __restrict__ cb) {
    const size_t NV = 2097152;
    size_t i = (size_t)blockIdx.x * 256 + threadIdx.x;
    const float4* src = (i < NV) ? (const float4*)x : (const float4*)ctx;
    short* dst = (i < NV) ? xb : cb;
    size_t idx = (i < NV) ? i : i - NV;
    float4 v = src[idx];
    short4 o;
    o.x = f2s(v.x); o.y = f2s(v.y); o.z = f2s(v.z); o.w = f2s(v.w);
    ((short4*)dst)[idx] = o;
}

// ---------------- prep: W -> W^T bf16 (K+V halves contiguous in WkvT) ----------------
__global__ __launch_bounds__(256) void transpose_weights(
    const float* __restrict__ q_w, const float* __restrict__ kv_w,
    const float* __restrict__ proj_w,
    short* __restrict__ WqT, short* __restrict__ WkvT, short* __restrict__ WpT) {
    __shared__ float t[32][33];
    const float* src; short* dst; int ld, coff;
    switch (blockIdx.z) {
        case 0:  src = q_w;    dst = WqT;                 ld = 1024; coff = 0;    break;
        case 1:  src = kv_w;   dst = WkvT;                ld = 2048; coff = 0;    break;
        case 2:  src = kv_w;   dst = WkvT + 1024 * 1024;  ld = 2048; coff = 1024; break;
        default: src = proj_w; dst = WpT;                 ld = 1024; coff = 0;    break;
    }
    int n0 = blockIdx.x * 32, k0 = blockIdx.y * 32;
    int tx = threadIdx.x & 31, ty = threadIdx.x >> 5;
    #pragma unroll
    for (int j = 0; j < 32; j += 8)
        t[ty + j][tx] = src[(size_t)(k0 + ty + j) * ld + coff + n0 + tx];
    __syncthreads();
    #pragma unroll
    for (int j = 0; j < 32; j += 8)
        dst[(size_t)(n0 + ty + j) * 1024 + k0 + tx] = f2s(t[tx][ty + j]);
}

// ---------------- GEMM 128x128, K=1024, 3-buffer counted-vmcnt pipeline ----------------
// grid: x = m-tile (XCD affinity: same-A-panel blocks co-located), y = n-tile.
// MODE 0: Q proj -> per-head LN -> RoPE -> *0.125*log2e -> Q[b,h,s,64] bf16
// MODE 1: KV proj (N=2048): n0<1024 -> K path (LN -> K[b,h,sc,64]); else V path
// MODE 2: out proj -> + bias -> fp32 out
template <int MODE>
__global__ __launch_bounds__(256) void gemm128(
    const short* __restrict__ A,    // [8192][1024] bf16 row-major
    const short* __restrict__ Bt,   // [N][1024] bf16 (N-major, K contiguous)
    const float* __restrict__ ln_scale,
    const float* __restrict__ ln_bias,
    short* __restrict__ outB,
    short* __restrict__ outB2,
    float* __restrict__ outF,
    const float* __restrict__ bias_vec) {
    // staging: 3 bufs x (A 128x32 + B 128x32) = 24576 shorts (48KB);
    // epilogue overlay 128x132 (16896 shorts) fits inside.
    __shared__ short smem[24576];
    const int tid = threadIdx.x;
    const int w = tid >> 6, lane = tid & 63, quad = lane >> 4, l15 = lane & 15;
    const int wr = w & 1, wc = w >> 1;
    const int m0 = blockIdx.x * 128, n0 = blockIdx.y * 128;  // x=m, y=n (XCD=m%8)

    const int srow = lane >> 2, slot = lane & 3;
    const int kslot = (slot ^ ((srow >> 1) & 3)) * 8;  // XOR swizzle: 2-way banks on read
    const short* Ag0 = A + (size_t)(m0 + w * 32 + srow) * 1024 + kslot;
    const short* Ag1 = Ag0 + (size_t)16 * 1024;
    const short* Bg0 = Bt + (size_t)(n0 + w * 32 + srow) * 1024 + kslot;
    const short* Bg1 = Bg0 + (size_t)16 * 1024;
    // wave w stages rows [w*32, w*32+32): 1024 shorts per tile (two 512-short gloads)
    short* Al = smem + w * 1024;           // + buf*8192
    short* Bl = smem + 4096 + w * 1024;    // + buf*8192

    f32x4 acc[4][4];
    #pragma unroll
    for (int r = 0; r < 4; r++)
        #pragma unroll
        for (int c = 0; c < 4; c++) acc[r][c] = f32x4{0.f, 0.f, 0.f, 0.f};

    const int rsw = (l15 >> 1) & 3;
    const int rch = (quad ^ rsw) * 8;

    // prologue: tile 0 -> buf0, tile 1 -> buf1; wait oldest 4 (tile 0) only.
    gload16(Al,              Ag0);
    gload16(Al + 512,        Ag1);
    gload16(Bl,              Bg0);
    gload16(Bl + 512,        Bg1);
    gload16(Al + 8192,       Ag0 + 32);
    gload16(Al + 8192 + 512, Ag1 + 32);
    gload16(Bl + 8192,       Bg0 + 32);
    gload16(Bl + 8192 + 512, Bg1 + 32);
    asm volatile("s_waitcnt vmcnt(4) lgkmcnt(0)" ::: "memory");
    __builtin_amdgcn_s_barrier();

    int curo = 0;       // current compute buffer offset (shorts)
    int pfo = 16384;    // prefetch target buffer offset (tile t+2)
    #pragma unroll 1
    for (int t = 0; t < 32; t++) {
        if (t < 30) {
            const int k0 = (t + 2) * 32;
            gload16(Al + pfo,       Ag0 + k0);
            gload16(Al + pfo + 512, Ag1 + k0);
            gload16(Bl + pfo,       Bg0 + k0);
            gload16(Bl + pfo + 512, Bg1 + k0);
        }
        bf16x8 af[4], bfr[4];
        #pragma unroll
        for (int rt = 0; rt < 4; rt++)
            af[rt] = *(const bf16x8*)(smem + curo + (wr * 64 + rt * 16 + l15) * 32 + rch);
        #pragma unroll
        for (int ct = 0; ct < 4; ct++)
            bfr[ct] = *(const bf16x8*)(smem + curo + 4096 + (wc * 64 + ct * 16 + l15) * 32 + rch);
        #pragma unroll
        for (int rt = 0; rt < 4; rt++)
            #pragma unroll
            for (int ct = 0; ct < 4; ct++)
                acc[rt][ct] = mfma16(af[rt], bfr[ct], acc[rt][ct]);
        // counted wait: tile t+1's 4 loads (oldest) must land; tile t+2's 4 may fly.
        if (t < 30) {
            asm volatile("s_waitcnt vmcnt(4) lgkmcnt(0)" ::: "memory");
        } else {
            asm volatile("s_waitcnt vmcnt(0) lgkmcnt(0)" ::: "memory");
        }
        __builtin_amdgcn_s_barrier();
        curo += 8192; if (curo == 24576) curo = 0;
        pfo  += 8192; if (pfo  == 24576) pfo  = 0;
    }

    // epilogue: lane holds C[row = wr*64+rt*16+quad*4+i][col = wc*64+ct*16+l15]
    const bool vpath = (MODE == 1) && (n0 >= 1024);
    if constexpr (MODE == 0 || MODE == 1) {
        if (!vpath) {
            #pragma unroll
            for (int rt = 0; rt < 4; rt++) {
                #pragma unroll
                for (int i = 0; i < 4; i++) {
                    float s = acc[rt][0][i] + acc[rt][1][i] + acc[rt][2][i] + acc[rt][3][i];
                    float q = acc[rt][0][i] * acc[rt][0][i] + acc[rt][1][i] * acc[rt][1][i] +
                              acc[rt][2][i] * acc[rt][2][i] + acc[rt][3][i] * acc[rt][3][i];
                    #pragma unroll
                    for (int off = 1; off < 16; off <<= 1) {
                        s += __shfl_xor(s, off, 64);
                        q += __shfl_xor(q, off, 64);
                    }
                    float mu = s * (1.f / 64.f);
                    float var = q * (1.f / 64.f) - mu * mu;
                    float rs = rsqrtf(var + 1e-5f);
                    float vals[4];
                    #pragma unroll
                    for (int ct = 0; ct < 4; ct++) {
                        int hd = ct * 16 + l15;
                        vals[ct] = (acc[rt][ct][i] - mu) * rs * ln_scale[hd] + ln_bias[hd];
                    }
                    if constexpr (MODE == 0) {  // RoPE pairs (hd, hd+32) = (ct, ct+2)
                        int sp = (m0 + wr * 64 + rt * 16 + quad * 4 + i) & 2047;
                        #pragma unroll
                        for (int ct = 0; ct < 2; ct++) {
                            int hd1 = ct * 16 + l15;
                            float ang = (float)sp * exp2f((float)hd1 * (-13.287712379549449f / 32.f));
                            float sn, cs;
                            sincosf(ang, &sn, &cs);
                            float v1 = vals[ct], v2 = vals[ct + 2];
                            vals[ct]     = v1 * cs - v2 * sn;
                            vals[ct + 2] = v1 * sn + v2 * cs;
                        }
                        // fold softmax scale*log2e into Q: attn exp2 arg = raw dot
                        #pragma unroll
                        for (int ct = 0; ct < 4; ct++) vals[ct] *= 0.1803368801f;
                    }
                    #pragma unroll
                    for (int ct = 0; ct < 4; ct++) acc[rt][ct][i] = vals[ct];
                }
            }
            drain_barrier();
            short* Csm = smem;  // overlay: [128][132] bf16, +4 pad
            #pragma unroll
            for (int rt = 0; rt < 4; rt++)
                #pragma unroll
                for (int ct = 0; ct < 4; ct++)
                    #pragma unroll
                    for (int i = 0; i < 4; i++)
                        Csm[(wr * 64 + rt * 16 + quad * 4 + i) * 132 + wc * 64 + ct * 16 + l15] =
                            f2s(acc[rt][ct][i]);
            drain_barrier();
            #pragma unroll
            for (int it = 0; it < 8; it++) {
                int row = it * 16 + (tid >> 4);
                int chunk = tid & 15;
                bf16x8 v = *(const bf16x8*)(Csm + row * 132 + chunk * 8);
                int hh = ((n0 & 1023) >> 6) + (chunk >> 3);
                int m = m0 + row, b = m >> 11, sp = m & 2047;
                *(bf16x8*)(outB + ((size_t)(b * 16 + hh) * 2048 + sp) * 64 + (chunk & 7) * 8) = v;
            }
        } else {
            // V path: transposed store V^T[b,h,hd,sc]
            const int b = m0 >> 11, h = ((n0 - 1024) >> 6) + wc;
            const int sp = (m0 & 2047) + wr * 64 + quad * 4;
            #pragma unroll
            for (int rt = 0; rt < 4; rt++)
                #pragma unroll
                for (int ct = 0; ct < 4; ct++) {
                    short4 pk;
                    pk.x = f2s(acc[rt][ct][0]); pk.y = f2s(acc[rt][ct][1]);
                    pk.z = f2s(acc[rt][ct][2]); pk.w = f2s(acc[rt][ct][3]);
                    int hd = ct * 16 + l15;
                    *(short4*)(outB2 + ((size_t)(b * 16 + h) * 64 + hd) * 2048 + sp + rt * 16) = pk;
                }
        }
    } else {
        #pragma unroll
        for (int rt = 0; rt < 4; rt++)
            #pragma unroll
            for (int i = 0; i < 4; i++) {
                size_t m = m0 + wr * 64 + rt * 16 + quad * 4 + i;
                #pragma unroll
                for (int ct = 0; ct < 4; ct++) {
                    int n = n0 + wc * 64 + ct * 16 + l15;
                    outF[m * 1024 + n] = acc[rt][ct][i] + bias_vec[n];
                }
            }
    }
}

// ---------------- attention: 2 q-tiles per block, tail-free (R10) ----------------
// S^T = K.Q^T with Q pre-scaled by 0.125*log2e -> p = exp2(st) (row offset
// dropped; cancels in normalization). grid (64,8): block handles q-tiles
// {qt, qt+8}. LDS: K 2buf | V 2buf | P_A | P_B = 68KB -> 2 blocks/CU.
__global__ __launch_bounds__(256, 2) void attn_kernel(
    const short* __restrict__ Q,   // [64][2048][64]
    const short* __restrict__ K,   // [64][2048][64]
    const short* __restrict__ V,   // [64][64][2048]  (V^T)
    short* __restrict__ AO) {      // [8192][1024] bf16
    __shared__ short smem[8192 + 8192 + 2 * 4 * 32 * 72];
    const int tid = threadIdx.x;
    const int w = tid >> 6, lane = tid & 63, quad = lane >> 4, l15 = lane & 15;
    const int bh = blockIdx.x, qt = blockIdx.y;  // grid (64,8): head -> XCD = bh%8
    const short* Qb = Q + (size_t)bh * 2048 * 64;
    const short* Kb = K + (size_t)bh * 2048 * 64;
    const short* Vb = V + (size_t)bh * 64 * 2048;
    const int q0g[2] = {qt * 128 + w * 32, (qt + 8) * 128 + w * 32};

    const int srow = lane >> 2, slot = lane & 3;
    const int sw = (slot ^ ((srow >> 1) & 3)) * 8;
    const short* Kg = Kb + (size_t)(w * 16 + srow) * 64 + sw;
    const short* Vg = Vb + (size_t)(w * 16 + srow) * 2048 + sw;
    short* Kl0 = smem + w * 512;           // 16 rows/wave/plane
    short* Vl0 = smem + 8192 + w * 512;

    bf16x8 bq[2][2][2];  // [group][nt][ks]: Q as B-operand B[n=qrow][k=hd]
    #pragma unroll
    for (int g = 0; g < 2; g++)
        #pragma unroll
        for (int nt = 0; nt < 2; nt++)
            #pragma unroll
            for (int ks = 0; ks < 2; ks++)
                bq[g][nt][ks] =
                    *(const bf16x8*)(Qb + (size_t)(q0g[g] + nt * 16 + l15) * 64 + ks * 32 + quad * 8);

    f32x4 acco[2][4][2];  // [group][ct(hd)][nt(qrow)] O^T
    #pragma unroll
    for (int g = 0; g < 2; g++)
        #pragma unroll
        for (int ct = 0; ct < 4; ct++)
            #pragma unroll
            for (int nt = 0; nt < 2; nt++) acco[g][ct][nt] = f32x4{0.f, 0.f, 0.f, 0.f};
    float lsum[2][2] = {{0.f, 0.f}, {0.f, 0.f}};
    const int rsw = (l15 >> 1) & 3;
    const int rch = (quad ^ rsw) * 8;

    gload16(Kl0,        Kg);
    gload16(Kl0 + 2048, Kg + 32);
    gload16(Vl0,        Vg);
    gload16(Vl0 + 2048, Vg + 32);
    drain_barrier();

    #pragma unroll 1
    for (int t = 0; t < 32; t++) {
        const int cur = (t & 1) * 4096;
        if (t < 31) {
            const int nxt = 4096 - cur;
            const int sc = (t + 1) * 64;
            gload16(Kl0 + nxt,        Kg + sc * 64);
            gload16(Kl0 + nxt + 2048, Kg + sc * 64 + 32);
            gload16(Vl0 + nxt,        Vg + sc);
            gload16(Vl0 + nxt + 2048, Vg + sc + 32);
        }
        // ---- phase 1: K fragments, QK^T + exp2 + P stores for both groups ----
        bf16x8 ak[4][2];
        #pragma unroll
        for (int mt = 0; mt < 4; mt++)
            #pragma unroll
            for (int ks = 0; ks < 2; ks++)
                ak[mt][ks] = *(const bf16x8*)(smem + cur + ks * 2048 + (mt * 16 + l15) * 32 + rch);

        #pragma unroll
        for (int g = 0; g < 2; g++) {
            short* Pw = smem + 16384 + g * 9216 + w * 2304;
            #pragma unroll
            for (int mt = 0; mt < 4; mt++) {
                #pragma unroll
                for (int nt = 0; nt < 2; nt++) {
                    f32x4 st = f32x4{0.f, 0.f, 0.f, 0.f};
                    st = mfma16(ak[mt][0], bq[g][nt][0], st);
                    st = mfma16(ak[mt][1], bq[g][nt][1], st);
                    float e0 = __builtin_amdgcn_exp2f(st[0]);
                    float e1 = __builtin_amdgcn_exp2f(st[1]);
                    float e2 = __builtin_amdgcn_exp2f(st[2]);
                    float e3 = __builtin_amdgcn_exp2f(st[3]);
                    lsum[g][nt] += (e0 + e1) + (e2 + e3);
                    unsigned int p01 = __builtin_amdgcn_perm(fbits(e1), fbits(e0), 0x07060302u);
                    unsigned int p23 = __builtin_amdgcn_perm(fbits(e3), fbits(e2), 0x07060302u);
                    uint2 pw;
                    pw.x = p01; pw.y = p23;
                    *(uint2*)(Pw + (nt * 16 + l15) * 72 + mt * 16 + quad * 4) = pw;
                }
            }
        }
        // P written via uint2*, read via bf16x8*: fence pins program order
        // (wave-local LDS ops execute in issue order -> order == correctness).
        asm volatile("" ::: "memory");

        // ---- phase 2: V fragments, P reads + PV for both groups ----
        bf16x8 av[4][2];
        #pragma unroll
        for (int ct = 0; ct < 4; ct++)
            #pragma unroll
            for (int ks = 0; ks < 2; ks++)
                av[ct][ks] = *(const bf16x8*)(smem + 8192 + cur + ks * 2048 + (ct * 16 + l15) * 32 + rch);

        #pragma unroll
        for (int g = 0; g < 2; g++) {
            short* Pw = smem + 16384 + g * 9216 + w * 2304;
            bf16x8 bp[2][2];
            #pragma unroll
            for (int nt = 0; nt < 2; nt++)
                #pragma unroll
                for (int ks = 0; ks < 2; ks++)
                    bp[nt][ks] = *(const bf16x8*)(Pw + (nt * 16 + l15) * 72 + ks * 32 + quad * 8);
            #pragma unroll
            for (int ct = 0; ct < 4; ct++)
                #pragma unroll
                for (int nt = 0; nt < 2; nt++)
                    #pragma unroll
                    for (int ks = 0; ks < 2; ks++)
                        acco[g][ct][nt] = mfma16(av[ct][ks], bp[nt][ks], acco[g][ct][nt]);
        }
        drain_barrier();
    }

    #pragma unroll
    for (int g = 0; g < 2; g++)
        #pragma unroll
        for (int nt = 0; nt < 2; nt++) {
            lsum[g][nt] += __shfl_xor(lsum[g][nt], 16, 64);
            lsum[g][nt] += __shfl_xor(lsum[g][nt], 32, 64);
        }
    const int b = bh >> 4, h = bh & 15;
    #pragma unroll
    for (int g = 0; g < 2; g++)
        #pragma unroll
        for (int nt = 0; nt < 2; nt++) {
            float inv = 1.f / lsum[g][nt];
            int sq = q0g[g] + nt * 16 + l15;
            #pragma unroll
            for (int ct = 0; ct < 4; ct++) {
                short4 pk;
                pk.x = f2s(acco[g][ct][nt][0] * inv); pk.y = f2s(acco[g][ct][nt][1] * inv);
                pk.z = f2s(acco[g][ct][nt][2] * inv); pk.w = f2s(acco[g][ct][nt][3] * inv);
                *(short4*)(AO + ((size_t)b * 2048 + sq) * 1024 + h * 64 + ct * 16 + quad * 4) = pk;
            }
        }
}

extern "C" void kernel_launch(void* const* d_in, const int* in_sizes, int n_in,
                              void* d_out, int out_size, void* d_ws, size_t ws_size,
                              hipStream_t stream) {
    (void)in_sizes; (void)n_in; (void)out_size; (void)ws_size;
    const float* x      = (const float*)d_in[0];
    const float* ctx    = (const float*)d_in[1];
    const float* q_w    = (const float*)d_in[2];
    const float* kv_w   = (const float*)d_in[3];
    const float* qn_s   = (const float*)d_in[4];
    const float* qn_b   = (const float*)d_in[5];
    const float* kn_s   = (const float*)d_in[6];
    const float* kn_b   = (const float*)d_in[7];
    const float* proj_w = (const float*)d_in[8];
    const float* proj_b = (const float*)d_in[9];
    float* out = (float*)d_out;

    char* ws = (char*)d_ws;
    const size_t MB = 1024 * 1024;
    short* xb   = (short*)(ws + 0 * MB);
    short* cb   = (short*)(ws + 16 * MB);
    short* Qb   = (short*)(ws + 32 * MB);   // [64][2048][64] post LN+RoPE+scale
    short* Kb   = (short*)(ws + 48 * MB);   // [64][2048][64] post LN
    short* Vt   = (short*)(ws + 64 * MB);   // [64][64][2048]
    short* AO   = (short*)(ws + 80 * MB);   // [8192][1024]
    short* WqT  = (short*)(ws + 96 * MB);   // 2MB
    short* WkvT = (short*)(ws + 98 * MB);   // 4MB  [2048][1024]
    short* WpT  = (short*)(ws + 102 * MB);  // 2MB

    conv_to_bf16<<<16384, 256, 0, stream>>>(x, ctx, xb, cb);
    transpose_weights<<<dim3(32, 32, 4), 256, 0, stream>>>(q_w, kv_w, proj_w, WqT, WkvT, WpT);
    gemm128<0><<<dim3(64, 8), 256, 0, stream>>>(xb, WqT, qn_s, qn_b, Qb, nullptr, nullptr, nullptr);
    gemm128<1><<<dim3(64, 16), 256, 0, stream>>>(cb, WkvT, kn_s, kn_b, Kb, Vt, nullptr, nullptr);
    attn_kernel<<<dim3(64, 8), 256, 0, stream>>>(Qb, Kb, Vt, AO);
    gemm128<2><<<dim3(64, 8), 256, 0, stream>>>(AO, WpT, nullptr, nullptr, nullptr, nullptr, out, proj_b);
}

// Round 7
// 304.679 us; speedup vs baseline: 1.1388x; 1.0641x over previous
//
#include <hip/hip_runtime.h>
#include <hip/hip_bf16.h>

// CrossAttention R13 = R12 + fused QKV dispatch + __launch_bounds__(256,3).
//  - R12 post-mortem: grid swap fixed FETCH (67.8->18.2MB) but dur unchanged
//    (90us, MfmaUtil 7%): latency-bound, ~1-2 blocks/CU resident (VGPR 192
//    caps 2 waves/SIMD; Occ 11%). K-loop schedule is NOT the lever -- wave
//    count is. Four schedule variants all gave ~90us.
//  - Fix 1: fuse Q-proj and KV-proj into ONE dispatch, grid (64,24): y<8 ->
//    Q path (xb@WqT, LN+RoPE+scale -> Qb), else KV path (cb@WkvT, LN -> Kb /
//    V^T -> Vt). 1536 blocks queued; removes serialization of two 7%-util
//    dispatches + tails.
//  - Fix 2: __launch_bounds__(256,3): VGPR<=170 -> 3 waves/SIMD -> 3 blocks/CU
//    (m97's proven occupancy config, same inner loop).
//  - attn: R10 structure, unchanged (89.5us).

typedef short bf16x8 __attribute__((ext_vector_type(8)));
typedef float f32x4 __attribute__((ext_vector_type(4)));

__device__ __forceinline__ short f2s(float f) {
    __hip_bfloat16 h = __float2bfloat16(f);
    return __builtin_bit_cast(short, h);
}

__device__ __forceinline__ f32x4 mfma16(bf16x8 a, bf16x8 b, f32x4 c) {
    return __builtin_amdgcn_mfma_f32_16x16x32_bf16(a, b, c, 0, 0, 0);
}

__device__ __forceinline__ void gload16(short* lds, const short* g) {
    __builtin_amdgcn_global_load_lds((const __attribute__((address_space(1))) void*)g,
                                     (__attribute__((address_space(3))) void*)lds,
                                     16, 0, 0);
}

// Barrier with guaranteed counter drain (correctness of single-barrier dbuf).
__device__ __forceinline__ void drain_barrier() {
    asm volatile("s_waitcnt vmcnt(0) lgkmcnt(0)" ::: "memory");
    __syncthreads();
}

__device__ __forceinline__ unsigned int fbits(float f) {
    return __builtin_bit_cast(unsigned int, f);
}

// ---------------- prep: fp32 -> bf16 for activations ----------------
__global__ __launch_bounds__(256) void conv_to_bf16(const float* __restrict__ x,
                                                    const float* __restrict__ ctx,
                                                    short* __restrict__ xb,
                                                    short* __restrict__ cb) {
    const size_t NV = 2097152;
    size_t i = (size_t)blockIdx.x * 256 + threadIdx.x;
    const float4* src = (i < NV) ? (const float4*)x : (const float4*)ctx;
    short* dst = (i < NV) ? xb : cb;
    size_t idx = (i < NV) ? i : i - NV;
    float4 v = src[idx];
    short4 o;
    o.x = f2s(v.x); o.y = f2s(v.y); o.z = f2s(v.z); o.w = f2s(v.w);
    ((short4*)dst)[idx] = o;
}

// ---------------- prep: W -> W^T bf16 (K+V halves contiguous in WkvT) ----------------
__global__ __launch_bounds__(256) void transpose_weights(
    const float* __restrict__ q_w, const float* __restrict__ kv_w,
    const float* __restrict__ proj_w,
    short* __restrict__ WqT, short* __restrict__ WkvT, short* __restrict__ WpT) {
    __shared__ float t[32][33];
    const float* src; short* dst; int ld, coff;
    switch (blockIdx.z) {
        case 0:  src = q_w;    dst = WqT;                 ld = 1024; coff = 0;    break;
        case 1:  src = kv_w;   dst = WkvT;                ld = 2048; coff = 0;    break;
        case 2:  src = kv_w;   dst = WkvT + 1024 * 1024;  ld = 2048; coff = 1024; break;
        default: src = proj_w; dst = WpT;                 ld = 1024; coff = 0;    break;
    }
    int n0 = blockIdx.x * 32, k0 = blockIdx.y * 32;
    int tx = threadIdx.x & 31, ty = threadIdx.x >> 5;
    #pragma unroll
    for (int j = 0; j < 32; j += 8)
        t[ty + j][tx] = src[(size_t)(k0 + ty + j) * ld + coff + n0 + tx];
    __syncthreads();
    #pragma unroll
    for (int j = 0; j < 32; j += 8)
        dst[(size_t)(n0 + ty + j) * 1024 + k0 + tx] = f2s(t[tx][ty + j]);
}

// ---------------- GEMM 128x128, K=1024, 3-buffer counted-vmcnt pipeline ----------------
// grid: x = m-tile (XCD affinity: same-A-panel blocks co-located), y = n-tile.
// MODE 3: fused QKV. y<8: Q path (A@Bt, LN(qn)+RoPE+scale -> outQ);
//         y>=8: KV path (A2@Bt2, n0=(y-8)*128; n0<1024: LN(kn) -> outK;
//         else V^T -> outV).
// MODE 2: out proj -> + bias -> fp32 outF.
template <int MODE>
__global__ __launch_bounds__(256, 3) void gemm128(
    const short* __restrict__ A,      // Q-path A (xb) / mode2 A (AO)
    const short* __restrict__ Bt,     // Q-path Bt (WqT) / mode2 Bt (WpT)
    const short* __restrict__ A2,     // KV-path A (cb)
    const short* __restrict__ Bt2,    // KV-path Bt (WkvT)
    const float* __restrict__ qn_scale, const float* __restrict__ qn_bias,
    const float* __restrict__ kn_scale, const float* __restrict__ kn_bias,
    short* __restrict__ outQ, short* __restrict__ outK, short* __restrict__ outV,
    float* __restrict__ outF, const float* __restrict__ bias_vec) {
    // staging: 3 bufs x (A 128x32 + B 128x32) = 24576 shorts (48KB);
    // epilogue overlay 128x132 (16896 shorts) fits inside.
    __shared__ short smem[24576];
    const int tid = threadIdx.x;
    const int w = tid >> 6, lane = tid & 63, quad = lane >> 4, l15 = lane & 15;
    const int wr = w & 1, wc = w >> 1;
    const int m0 = blockIdx.x * 128;  // x=m (XCD=m%8)

    int n0;
    bool qpath = true, vpath = false;
    const short *Ab, *Bb;
    const float *lns = qn_scale, *lnb = qn_bias;
    if constexpr (MODE == 3) {
        const int y = blockIdx.y;
        qpath = (y < 8);
        n0 = qpath ? y * 128 : (y - 8) * 128;
        Ab = qpath ? A : A2;
        Bb = qpath ? Bt : Bt2;
        lns = qpath ? qn_scale : kn_scale;
        lnb = qpath ? qn_bias : kn_bias;
        vpath = (!qpath) && (n0 >= 1024);
    } else {
        n0 = blockIdx.y * 128;
        Ab = A; Bb = Bt;
    }

    const int srow = lane >> 2, slot = lane & 3;
    const int kslot = (slot ^ ((srow >> 1) & 3)) * 8;  // XOR swizzle: 2-way banks on read
    const short* Ag0 = Ab + (size_t)(m0 + w * 32 + srow) * 1024 + kslot;
    const short* Ag1 = Ag0 + (size_t)16 * 1024;
    const short* Bg0 = Bb + (size_t)(n0 + w * 32 + srow) * 1024 + kslot;
    const short* Bg1 = Bg0 + (size_t)16 * 1024;
    // wave w stages rows [w*32, w*32+32): 1024 shorts per tile (two 512-short gloads)
    short* Al = smem + w * 1024;           // + buf*8192
    short* Bl = smem + 4096 + w * 1024;    // + buf*8192

    f32x4 acc[4][4];
    #pragma unroll
    for (int r = 0; r < 4; r++)
        #pragma unroll
        for (int c = 0; c < 4; c++) acc[r][c] = f32x4{0.f, 0.f, 0.f, 0.f};

    const int rsw = (l15 >> 1) & 3;
    const int rch = (quad ^ rsw) * 8;

    // prologue: tile 0 -> buf0, tile 1 -> buf1; wait oldest 4 (tile 0) only.
    gload16(Al,              Ag0);
    gload16(Al + 512,        Ag1);
    gload16(Bl,              Bg0);
    gload16(Bl + 512,        Bg1);
    gload16(Al + 8192,       Ag0 + 32);
    gload16(Al + 8192 + 512, Ag1 + 32);
    gload16(Bl + 8192,       Bg0 + 32);
    gload16(Bl + 8192 + 512, Bg1 + 32);
    asm volatile("s_waitcnt vmcnt(4) lgkmcnt(0)" ::: "memory");
    __builtin_amdgcn_s_barrier();

    int curo = 0;       // current compute buffer offset (shorts)
    int pfo = 16384;    // prefetch target buffer offset (tile t+2)
    #pragma unroll 1
    for (int t = 0; t < 32; t++) {
        if (t < 30) {
            const int k0 = (t + 2) * 32;
            gload16(Al + pfo,       Ag0 + k0);
            gload16(Al + pfo + 512, Ag1 + k0);
            gload16(Bl + pfo,       Bg0 + k0);
            gload16(Bl + pfo + 512, Bg1 + k0);
        }
        bf16x8 af[4], bfr[4];
        #pragma unroll
        for (int rt = 0; rt < 4; rt++)
            af[rt] = *(const bf16x8*)(smem + curo + (wr * 64 + rt * 16 + l15) * 32 + rch);
        #pragma unroll
        for (int ct = 0; ct < 4; ct++)
            bfr[ct] = *(const bf16x8*)(smem + curo + 4096 + (wc * 64 + ct * 16 + l15) * 32 + rch);
        #pragma unroll
        for (int rt = 0; rt < 4; rt++)
            #pragma unroll
            for (int ct = 0; ct < 4; ct++)
                acc[rt][ct] = mfma16(af[rt], bfr[ct], acc[rt][ct]);
        // counted wait: tile t+1's 4 loads (oldest) must land; tile t+2's 4 may fly.
        if (t < 30) {
            asm volatile("s_waitcnt vmcnt(4) lgkmcnt(0)" ::: "memory");
        } else {
            asm volatile("s_waitcnt vmcnt(0) lgkmcnt(0)" ::: "memory");
        }
        __builtin_amdgcn_s_barrier();
        curo += 8192; if (curo == 24576) curo = 0;
        pfo  += 8192; if (pfo  == 24576) pfo  = 0;
    }

    // epilogue: lane holds C[row = wr*64+rt*16+quad*4+i][col = wc*64+ct*16+l15]
    if constexpr (MODE == 3) {
        if (!vpath) {
            #pragma unroll
            for (int rt = 0; rt < 4; rt++) {
                #pragma unroll
                for (int i = 0; i < 4; i++) {
                    float s = acc[rt][0][i] + acc[rt][1][i] + acc[rt][2][i] + acc[rt][3][i];
                    float q = acc[rt][0][i] * acc[rt][0][i] + acc[rt][1][i] * acc[rt][1][i] +
                              acc[rt][2][i] * acc[rt][2][i] + acc[rt][3][i] * acc[rt][3][i];
                    #pragma unroll
                    for (int off = 1; off < 16; off <<= 1) {
                        s += __shfl_xor(s, off, 64);
                        q += __shfl_xor(q, off, 64);
                    }
                    float mu = s * (1.f / 64.f);
                    float var = q * (1.f / 64.f) - mu * mu;
                    float rs = rsqrtf(var + 1e-5f);
                    float vals[4];
                    #pragma unroll
                    for (int ct = 0; ct < 4; ct++) {
                        int hd = ct * 16 + l15;
                        vals[ct] = (acc[rt][ct][i] - mu) * rs * lns[hd] + lnb[hd];
                    }
                    if (qpath) {  // RoPE pairs (hd, hd+32) = (ct, ct+2), then *0.125*log2e
                        int sp = (m0 + wr * 64 + rt * 16 + quad * 4 + i) & 2047;
                        #pragma unroll
                        for (int ct = 0; ct < 2; ct++) {
                            int hd1 = ct * 16 + l15;
                            float ang = (float)sp * exp2f((float)hd1 * (-13.287712379549449f / 32.f));
                            float sn, cs;
                            sincosf(ang, &sn, &cs);
                            float v1 = vals[ct], v2 = vals[ct + 2];
                            vals[ct]     = v1 * cs - v2 * sn;
                            vals[ct + 2] = v1 * sn + v2 * cs;
                        }
                        #pragma unroll
                        for (int ct = 0; ct < 4; ct++) vals[ct] *= 0.1803368801f;
                    }
                    #pragma unroll
                    for (int ct = 0; ct < 4; ct++) acc[rt][ct][i] = vals[ct];
                }
            }
            drain_barrier();
            short* Csm = smem;  // overlay: [128][132] bf16, +4 pad
            #pragma unroll
            for (int rt = 0; rt < 4; rt++)
                #pragma unroll
                for (int ct = 0; ct < 4; ct++)
                    #pragma unroll
                    for (int i = 0; i < 4; i++)
                        Csm[(wr * 64 + rt * 16 + quad * 4 + i) * 132 + wc * 64 + ct * 16 + l15] =
                            f2s(acc[rt][ct][i]);
            drain_barrier();
            short* dst = qpath ? outQ : outK;
            #pragma unroll
            for (int it = 0; it < 8; it++) {
                int row = it * 16 + (tid >> 4);
                int chunk = tid & 15;
                bf16x8 v = *(const bf16x8*)(Csm + row * 132 + chunk * 8);
                int hh = ((n0 & 1023) >> 6) + (chunk >> 3);
                int m = m0 + row, b = m >> 11, sp = m & 2047;
                *(bf16x8*)(dst + ((size_t)(b * 16 + hh) * 2048 + sp) * 64 + (chunk & 7) * 8) = v;
            }
        } else {
            // V path: transposed store V^T[b,h,hd,sc]
            const int b = m0 >> 11, h = ((n0 - 1024) >> 6) + wc;
            const int sp = (m0 & 2047) + wr * 64 + quad * 4;
            #pragma unroll
            for (int rt = 0; rt < 4; rt++)
                #pragma unroll
                for (int ct = 0; ct < 4; ct++) {
                    short4 pk;
                    pk.x = f2s(acc[rt][ct][0]); pk.y = f2s(acc[rt][ct][1]);
                    pk.z = f2s(acc[rt][ct][2]); pk.w = f2s(acc[rt][ct][3]);
                    int hd = ct * 16 + l15;
                    *(short4*)(outV + ((size_t)(b * 16 + h) * 64 + hd) * 2048 + sp + rt * 16) = pk;
                }
        }
    } else {
        #pragma unroll
        for (int rt = 0; rt < 4; rt++)
            #pragma unroll
            for (int i = 0; i < 4; i++) {
                size_t m = m0 + wr * 64 + rt * 16 + quad * 4 + i;
                #pragma unroll
                for (int ct = 0; ct < 4; ct++) {
                    int n = n0 + wc * 64 + ct * 16 + l15;
                    outF[m * 1024 + n] = acc[rt][ct][i] + bias_vec[n];
                }
            }
    }
}

// ---------------- attention: 2 q-tiles per block, tail-free (R10) ----------------
// S^T = K.Q^T with Q pre-scaled by 0.125*log2e -> p = exp2(st) (row offset
// dropped; cancels in normalization). grid (64,8): block handles q-tiles
// {qt, qt+8}. LDS: K 2buf | V 2buf | P_A | P_B = 68KB -> 2 blocks/CU.
__global__ __launch_bounds__(256, 2) void attn_kernel(
    const short* __restrict__ Q,   // [64][2048][64]
    const short* __restrict__ K,   // [64][2048][64]
    const short* __restrict__ V,   // [64][64][2048]  (V^T)
    short* __restrict__ AO) {      // [8192][1024] bf16
    __shared__ short smem[8192 + 8192 + 2 * 4 * 32 * 72];
    const int tid = threadIdx.x;
    const int w = tid >> 6, lane = tid & 63, quad = lane >> 4, l15 = lane & 15;
    const int bh = blockIdx.x, qt = blockIdx.y;  // grid (64,8): head -> XCD = bh%8
    const short* Qb = Q + (size_t)bh * 2048 * 64;
    const short* Kb = K + (size_t)bh * 2048 * 64;
    const short* Vb = V + (size_t)bh * 64 * 2048;
    const int q0g[2] = {qt * 128 + w * 32, (qt + 8) * 128 + w * 32};

    const int srow = lane >> 2, slot = lane & 3;
    const int sw = (slot ^ ((srow >> 1) & 3)) * 8;
    const short* Kg = Kb + (size_t)(w * 16 + srow) * 64 + sw;
    const short* Vg = Vb + (size_t)(w * 16 + srow) * 2048 + sw;
    short* Kl0 = smem + w * 512;           // 16 rows/wave/plane
    short* Vl0 = smem + 8192 + w * 512;

    bf16x8 bq[2][2][2];  // [group][nt][ks]: Q as B-operand B[n=qrow][k=hd]
    #pragma unroll
    for (int g = 0; g < 2; g++)
        #pragma unroll
        for (int nt = 0; nt < 2; nt++)
            #pragma unroll
            for (int ks = 0; ks < 2; ks++)
                bq[g][nt][ks] =
                    *(const bf16x8*)(Qb + (size_t)(q0g[g] + nt * 16 + l15) * 64 + ks * 32 + quad * 8);

    f32x4 acco[2][4][2];  // [group][ct(hd)][nt(qrow)] O^T
    #pragma unroll
    for (int g = 0; g < 2; g++)
        #pragma unroll
        for (int ct = 0; ct < 4; ct++)
            #pragma unroll
            for (int nt = 0; nt < 2; nt++) acco[g][ct][nt] = f32x4{0.f, 0.f, 0.f, 0.f};
    float lsum[2][2] = {{0.f, 0.f}, {0.f, 0.f}};
    const int rsw = (l15 >> 1) & 3;
    const int rch = (quad ^ rsw) * 8;

    gload16(Kl0,        Kg);
    gload16(Kl0 + 2048, Kg + 32);
    gload16(Vl0,        Vg);
    gload16(Vl0 + 2048, Vg + 32);
    drain_barrier();

    #pragma unroll 1
    for (int t = 0; t < 32; t++) {
        const int cur = (t & 1) * 4096;
        if (t < 31) {
            const int nxt = 4096 - cur;
            const int sc = (t + 1) * 64;
            gload16(Kl0 + nxt,        Kg + sc * 64);
            gload16(Kl0 + nxt + 2048, Kg + sc * 64 + 32);
            gload16(Vl0 + nxt,        Vg + sc);
            gload16(Vl0 + nxt + 2048, Vg + sc + 32);
        }
        // ---- phase 1: K fragments, QK^T + exp2 + P stores for both groups ----
        bf16x8 ak[4][2];
        #pragma unroll
        for (int mt = 0; mt < 4; mt++)
            #pragma unroll
            for (int ks = 0; ks < 2; ks++)
                ak[mt][ks] = *(const bf16x8*)(smem + cur + ks * 2048 + (mt * 16 + l15) * 32 + rch);

        #pragma unroll
        for (int g = 0; g < 2; g++) {
            short* Pw = smem + 16384 + g * 9216 + w * 2304;
            #pragma unroll
            for (int mt = 0; mt < 4; mt++) {
                #pragma unroll
                for (int nt = 0; nt < 2; nt++) {
                    f32x4 st = f32x4{0.f, 0.f, 0.f, 0.f};
                    st = mfma16(ak[mt][0], bq[g][nt][0], st);
                    st = mfma16(ak[mt][1], bq[g][nt][1], st);
                    float e0 = __builtin_amdgcn_exp2f(st[0]);
                    float e1 = __builtin_amdgcn_exp2f(st[1]);
                    float e2 = __builtin_amdgcn_exp2f(st[2]);
                    float e3 = __builtin_amdgcn_exp2f(st[3]);
                    lsum[g][nt] += (e0 + e1) + (e2 + e3);
                    unsigned int p01 = __builtin_amdgcn_perm(fbits(e1), fbits(e0), 0x07060302u);
                    unsigned int p23 = __builtin_amdgcn_perm(fbits(e3), fbits(e2), 0x07060302u);
                    uint2 pw;
                    pw.x = p01; pw.y = p23;
                    *(uint2*)(Pw + (nt * 16 + l15) * 72 + mt * 16 + quad * 4) = pw;
                }
            }
        }
        // P written via uint2*, read via bf16x8*: fence pins program order
        // (wave-local LDS ops execute in issue order -> order == correctness).
        asm volatile("" ::: "memory");

        // ---- phase 2: V fragments, P reads + PV for both groups ----
        bf16x8 av[4][2];
        #pragma unroll
        for (int ct = 0; ct < 4; ct++)
            #pragma unroll
            for (int ks = 0; ks < 2; ks++)
                av[ct][ks] = *(const bf16x8*)(smem + 8192 + cur + ks * 2048 + (ct * 16 + l15) * 32 + rch);

        #pragma unroll
        for (int g = 0; g < 2; g++) {
            short* Pw = smem + 16384 + g * 9216 + w * 2304;
            bf16x8 bp[2][2];
            #pragma unroll
            for (int nt = 0; nt < 2; nt++)
                #pragma unroll
                for (int ks = 0; ks < 2; ks++)
                    bp[nt][ks] = *(const bf16x8*)(Pw + (nt * 16 + l15) * 72 + ks * 32 + quad * 8);
            #pragma unroll
            for (int ct = 0; ct < 4; ct++)
                #pragma unroll
                for (int nt = 0; nt < 2; nt++)
                    #pragma unroll
                    for (int ks = 0; ks < 2; ks++)
                        acco[g][ct][nt] = mfma16(av[ct][ks], bp[nt][ks], acco[g][ct][nt]);
        }
        drain_barrier();
    }

    #pragma unroll
    for (int g = 0; g < 2; g++)
        #pragma unroll
        for (int nt = 0; nt < 2; nt++) {
            lsum[g][nt] += __shfl_xor(lsum[g][nt], 16, 64);
            lsum[g][nt] += __shfl_xor(lsum[g][nt], 32, 64);
        }
    const int b = bh >> 4, h = bh & 15;
    #pragma unroll
    for (int g = 0; g < 2; g++)
        #pragma unroll
        for (int nt = 0; nt < 2; nt++) {
            float inv = 1.f / lsum[g][nt];
            int sq = q0g[g] + nt * 16 + l15;
            #pragma unroll
            for (int ct = 0; ct < 4; ct++) {
                short4 pk;
                pk.x = f2s(acco[g][ct][nt][0] * inv); pk.y = f2s(acco[g][ct][nt][1] * inv);
                pk.z = f2s(acco[g][ct][nt][2] * inv); pk.w = f2s(acco[g][ct][nt][3] * inv);
                *(short4*)(AO + ((size_t)b * 2048 + sq) * 1024 + h * 64 + ct * 16 + quad * 4) = pk;
            }
        }
}

extern "C" void kernel_launch(void* const* d_in, const int* in_sizes, int n_in,
                              void* d_out, int out_size, void* d_ws, size_t ws_size,
                              hipStream_t stream) {
    (void)in_sizes; (void)n_in; (void)out_size; (void)ws_size;
    const float* x      = (const float*)d_in[0];
    const float* ctx    = (const float*)d_in[1];
    const float* q_w    = (const float*)d_in[2];
    const float* kv_w   = (const float*)d_in[3];
    const float* qn_s   = (const float*)d_in[4];
    const float* qn_b   = (const float*)d_in[5];
    const float* kn_s   = (const float*)d_in[6];
    const float* kn_b   = (const float*)d_in[7];
    const float* proj_w = (const float*)d_in[8];
    const float* proj_b = (const float*)d_in[9];
    float* out = (float*)d_out;

    char* ws = (char*)d_ws;
    const size_t MB = 1024 * 1024;
    short* xb   = (short*)(ws + 0 * MB);
    short* cb   = (short*)(ws + 16 * MB);
    short* Qb   = (short*)(ws + 32 * MB);   // [64][2048][64] post LN+RoPE+scale
    short* Kb   = (short*)(ws + 48 * MB);   // [64][2048][64] post LN
    short* Vt   = (short*)(ws + 64 * MB);   // [64][64][2048]
    short* AO   = (short*)(ws + 80 * MB);   // [8192][1024]
    short* WqT  = (short*)(ws + 96 * MB);   // 2MB
    short* WkvT = (short*)(ws + 98 * MB);   // 4MB  [2048][1024]
    short* WpT  = (short*)(ws + 102 * MB);  // 2MB

    conv_to_bf16<<<16384, 256, 0, stream>>>(x, ctx, xb, cb);
    transpose_weights<<<dim3(32, 32, 4), 256, 0, stream>>>(q_w, kv_w, proj_w, WqT, WkvT, WpT);
    gemm128<3><<<dim3(64, 24), 256, 0, stream>>>(xb, WqT, cb, WkvT, qn_s, qn_b, kn_s, kn_b,
                                                 Qb, Kb, Vt, nullptr, nullptr);
    attn_kernel<<<dim3(64, 8), 256, 0, stream>>>(Qb, Kb, Vt, AO);
    gemm128<2><<<dim3(64, 8), 256, 0, stream>>>(AO, WpT, nullptr, nullptr, nullptr, nullptr,
                                                nullptr, nullptr, nullptr, nullptr, nullptr,
                                                out, proj_b);
}

// Round 8
// 299.648 us; speedup vs baseline: 1.1580x; 1.0168x over previous
//
#include <hip/hip_runtime.h>
#include <hip/hip_bf16.h>

// CrossAttention R14 = R13 + attn 8-wave blocks (16 waves/CU).
//  - R13 post-mortem: fusion+bounds worked (304.7us); attn back on top at
//    87.6us with Occ 17.6% == 2 blocks/CU == 2 waves/SIMD. Block count (512)
//    binds residency, so the lever is waves PER block, not LDS.
//  - attn: 512-thread blocks, 8 waves, ONE 32-row q-group per wave (block =
//    256 q-rows, grid (64,8) unchanged). LDS still 68KB -> 2 blocks/CU =
//    16 waves/CU = 4 waves/SIMD (2x latency hiding). Per-wave VGPR halves
//    (one group) -> fits 128-VGPR/4-wave budget. Staging: waves 0-3 stage K,
//    waves 4-7 stage V (2 gloads/wave/iter). P wave-private as before.
//  - GEMMs: R13 fused QKV (grid 64x24) + mode2, __launch_bounds__(256,3),
//    3-buffer counted-vmcnt pipeline, XCD-affine grid (x=m).

typedef short bf16x8 __attribute__((ext_vector_type(8)));
typedef float f32x4 __attribute__((ext_vector_type(4)));

__device__ __forceinline__ short f2s(float f) {
    __hip_bfloat16 h = __float2bfloat16(f);
    return __builtin_bit_cast(short, h);
}

__device__ __forceinline__ f32x4 mfma16(bf16x8 a, bf16x8 b, f32x4 c) {
    return __builtin_amdgcn_mfma_f32_16x16x32_bf16(a, b, c, 0, 0, 0);
}

__device__ __forceinline__ void gload16(short* lds, const short* g) {
    __builtin_amdgcn_global_load_lds((const __attribute__((address_space(1))) void*)g,
                                     (__attribute__((address_space(3))) void*)lds,
                                     16, 0, 0);
}

// Barrier with guaranteed counter drain (correctness of single-barrier dbuf).
__device__ __forceinline__ void drain_barrier() {
    asm volatile("s_waitcnt vmcnt(0) lgkmcnt(0)" ::: "memory");
    __syncthreads();
}

__device__ __forceinline__ unsigned int fbits(float f) {
    return __builtin_bit_cast(unsigned int, f);
}

// ---------------- prep: fp32 -> bf16 for activations ----------------
__global__ __launch_bounds__(256) void conv_to_bf16(const float* __restrict__ x,
                                                    const float* __restrict__ ctx,
                                                    short* __restrict__ xb,
                                                    short* __restrict__ cb) {
    const size_t NV = 2097152;
    size_t i = (size_t)blockIdx.x * 256 + threadIdx.x;
    const float4* src = (i < NV) ? (const float4*)x : (const float4*)ctx;
    short* dst = (i < NV) ? xb : cb;
    size_t idx = (i < NV) ? i : i - NV;
    float4 v = src[idx];
    short4 o;
    o.x = f2s(v.x); o.y = f2s(v.y); o.z = f2s(v.z); o.w = f2s(v.w);
    ((short4*)dst)[idx] = o;
}

// ---------------- prep: W -> W^T bf16 (K+V halves contiguous in WkvT) ----------------
__global__ __launch_bounds__(256) void transpose_weights(
    const float* __restrict__ q_w, const float* __restrict__ kv_w,
    const float* __restrict__ proj_w,
    short* __restrict__ WqT, short* __restrict__ WkvT, short* __restrict__ WpT) {
    __shared__ float t[32][33];
    const float* src; short* dst; int ld, coff;
    switch (blockIdx.z) {
        case 0:  src = q_w;    dst = WqT;                 ld = 1024; coff = 0;    break;
        case 1:  src = kv_w;   dst = WkvT;                ld = 2048; coff = 0;    break;
        case 2:  src = kv_w;   dst = WkvT + 1024 * 1024;  ld = 2048; coff = 1024; break;
        default: src = proj_w; dst = WpT;                 ld = 1024; coff = 0;    break;
    }
    int n0 = blockIdx.x * 32, k0 = blockIdx.y * 32;
    int tx = threadIdx.x & 31, ty = threadIdx.x >> 5;
    #pragma unroll
    for (int j = 0; j < 32; j += 8)
        t[ty + j][tx] = src[(size_t)(k0 + ty + j) * ld + coff + n0 + tx];
    __syncthreads();
    #pragma unroll
    for (int j = 0; j < 32; j += 8)
        dst[(size_t)(n0 + ty + j) * 1024 + k0 + tx] = f2s(t[tx][ty + j]);
}

// ---------------- GEMM 128x128, K=1024, 3-buffer counted-vmcnt pipeline ----------------
// grid: x = m-tile (XCD affinity: same-A-panel blocks co-located), y = n-tile.
// MODE 3: fused QKV. y<8: Q path (A@Bt, LN(qn)+RoPE+scale -> outQ);
//         y>=8: KV path (A2@Bt2, n0=(y-8)*128; n0<1024: LN(kn) -> outK;
//         else V^T -> outV).
// MODE 2: out proj -> + bias -> fp32 outF.
template <int MODE>
__global__ __launch_bounds__(256, 3) void gemm128(
    const short* __restrict__ A,      // Q-path A (xb) / mode2 A (AO)
    const short* __restrict__ Bt,     // Q-path Bt (WqT) / mode2 Bt (WpT)
    const short* __restrict__ A2,     // KV-path A (cb)
    const short* __restrict__ Bt2,    // KV-path Bt (WkvT)
    const float* __restrict__ qn_scale, const float* __restrict__ qn_bias,
    const float* __restrict__ kn_scale, const float* __restrict__ kn_bias,
    short* __restrict__ outQ, short* __restrict__ outK, short* __restrict__ outV,
    float* __restrict__ outF, const float* __restrict__ bias_vec) {
    // staging: 3 bufs x (A 128x32 + B 128x32) = 24576 shorts (48KB);
    // epilogue overlay 128x132 (16896 shorts) fits inside.
    __shared__ short smem[24576];
    const int tid = threadIdx.x;
    const int w = tid >> 6, lane = tid & 63, quad = lane >> 4, l15 = lane & 15;
    const int wr = w & 1, wc = w >> 1;
    const int m0 = blockIdx.x * 128;  // x=m (XCD=m%8)

    int n0;
    bool qpath = true, vpath = false;
    const short *Ab, *Bb;
    const float *lns = qn_scale, *lnb = qn_bias;
    if constexpr (MODE == 3) {
        const int y = blockIdx.y;
        qpath = (y < 8);
        n0 = qpath ? y * 128 : (y - 8) * 128;
        Ab = qpath ? A : A2;
        Bb = qpath ? Bt : Bt2;
        lns = qpath ? qn_scale : kn_scale;
        lnb = qpath ? qn_bias : kn_bias;
        vpath = (!qpath) && (n0 >= 1024);
    } else {
        n0 = blockIdx.y * 128;
        Ab = A; Bb = Bt;
    }

    const int srow = lane >> 2, slot = lane & 3;
    const int kslot = (slot ^ ((srow >> 1) & 3)) * 8;  // XOR swizzle: 2-way banks on read
    const short* Ag0 = Ab + (size_t)(m0 + w * 32 + srow) * 1024 + kslot;
    const short* Ag1 = Ag0 + (size_t)16 * 1024;
    const short* Bg0 = Bb + (size_t)(n0 + w * 32 + srow) * 1024 + kslot;
    const short* Bg1 = Bg0 + (size_t)16 * 1024;
    // wave w stages rows [w*32, w*32+32): 1024 shorts per tile (two 512-short gloads)
    short* Al = smem + w * 1024;           // + buf*8192
    short* Bl = smem + 4096 + w * 1024;    // + buf*8192

    f32x4 acc[4][4];
    #pragma unroll
    for (int r = 0; r < 4; r++)
        #pragma unroll
        for (int c = 0; c < 4; c++) acc[r][c] = f32x4{0.f, 0.f, 0.f, 0.f};

    const int rsw = (l15 >> 1) & 3;
    const int rch = (quad ^ rsw) * 8;

    // prologue: tile 0 -> buf0, tile 1 -> buf1; wait oldest 4 (tile 0) only.
    gload16(Al,              Ag0);
    gload16(Al + 512,        Ag1);
    gload16(Bl,              Bg0);
    gload16(Bl + 512,        Bg1);
    gload16(Al + 8192,       Ag0 + 32);
    gload16(Al + 8192 + 512, Ag1 + 32);
    gload16(Bl + 8192,       Bg0 + 32);
    gload16(Bl + 8192 + 512, Bg1 + 32);
    asm volatile("s_waitcnt vmcnt(4) lgkmcnt(0)" ::: "memory");
    __builtin_amdgcn_s_barrier();

    int curo = 0;       // current compute buffer offset (shorts)
    int pfo = 16384;    // prefetch target buffer offset (tile t+2)
    #pragma unroll 1
    for (int t = 0; t < 32; t++) {
        if (t < 30) {
            const int k0 = (t + 2) * 32;
            gload16(Al + pfo,       Ag0 + k0);
            gload16(Al + pfo + 512, Ag1 + k0);
            gload16(Bl + pfo,       Bg0 + k0);
            gload16(Bl + pfo + 512, Bg1 + k0);
        }
        bf16x8 af[4], bfr[4];
        #pragma unroll
        for (int rt = 0; rt < 4; rt++)
            af[rt] = *(const bf16x8*)(smem + curo + (wr * 64 + rt * 16 + l15) * 32 + rch);
        #pragma unroll
        for (int ct = 0; ct < 4; ct++)
            bfr[ct] = *(const bf16x8*)(smem + curo + 4096 + (wc * 64 + ct * 16 + l15) * 32 + rch);
        #pragma unroll
        for (int rt = 0; rt < 4; rt++)
            #pragma unroll
            for (int ct = 0; ct < 4; ct++)
                acc[rt][ct] = mfma16(af[rt], bfr[ct], acc[rt][ct]);
        // counted wait: tile t+1's 4 loads (oldest) must land; tile t+2's 4 may fly.
        if (t < 30) {
            asm volatile("s_waitcnt vmcnt(4) lgkmcnt(0)" ::: "memory");
        } else {
            asm volatile("s_waitcnt vmcnt(0) lgkmcnt(0)" ::: "memory");
        }
        __builtin_amdgcn_s_barrier();
        curo += 8192; if (curo == 24576) curo = 0;
        pfo  += 8192; if (pfo  == 24576) pfo  = 0;
    }

    // epilogue: lane holds C[row = wr*64+rt*16+quad*4+i][col = wc*64+ct*16+l15]
    if constexpr (MODE == 3) {
        if (!vpath) {
            #pragma unroll
            for (int rt = 0; rt < 4; rt++) {
                #pragma unroll
                for (int i = 0; i < 4; i++) {
                    float s = acc[rt][0][i] + acc[rt][1][i] + acc[rt][2][i] + acc[rt][3][i];
                    float q = acc[rt][0][i] * acc[rt][0][i] + acc[rt][1][i] * acc[rt][1][i] +
                              acc[rt][2][i] * acc[rt][2][i] + acc[rt][3][i] * acc[rt][3][i];
                    #pragma unroll
                    for (int off = 1; off < 16; off <<= 1) {
                        s += __shfl_xor(s, off, 64);
                        q += __shfl_xor(q, off, 64);
                    }
                    float mu = s * (1.f / 64.f);
                    float var = q * (1.f / 64.f) - mu * mu;
                    float rs = rsqrtf(var + 1e-5f);
                    float vals[4];
                    #pragma unroll
                    for (int ct = 0; ct < 4; ct++) {
                        int hd = ct * 16 + l15;
                        vals[ct] = (acc[rt][ct][i] - mu) * rs * lns[hd] + lnb[hd];
                    }
                    if (qpath) {  // RoPE pairs (hd, hd+32) = (ct, ct+2), then *0.125*log2e
                        int sp = (m0 + wr * 64 + rt * 16 + quad * 4 + i) & 2047;
                        #pragma unroll
                        for (int ct = 0; ct < 2; ct++) {
                            int hd1 = ct * 16 + l15;
                            float ang = (float)sp * exp2f((float)hd1 * (-13.287712379549449f / 32.f));
                            float sn, cs;
                            sincosf(ang, &sn, &cs);
                            float v1 = vals[ct], v2 = vals[ct + 2];
                            vals[ct]     = v1 * cs - v2 * sn;
                            vals[ct + 2] = v1 * sn + v2 * cs;
                        }
                        #pragma unroll
                        for (int ct = 0; ct < 4; ct++) vals[ct] *= 0.1803368801f;
                    }
                    #pragma unroll
                    for (int ct = 0; ct < 4; ct++) acc[rt][ct][i] = vals[ct];
                }
            }
            drain_barrier();
            short* Csm = smem;  // overlay: [128][132] bf16, +4 pad
            #pragma unroll
            for (int rt = 0; rt < 4; rt++)
                #pragma unroll
                for (int ct = 0; ct < 4; ct++)
                    #pragma unroll
                    for (int i = 0; i < 4; i++)
                        Csm[(wr * 64 + rt * 16 + quad * 4 + i) * 132 + wc * 64 + ct * 16 + l15] =
                            f2s(acc[rt][ct][i]);
            drain_barrier();
            short* dst = qpath ? outQ : outK;
            #pragma unroll
            for (int it = 0; it < 8; it++) {
                int row = it * 16 + (tid >> 4);
                int chunk = tid & 15;
                bf16x8 v = *(const bf16x8*)(Csm + row * 132 + chunk * 8);
                int hh = ((n0 & 1023) >> 6) + (chunk >> 3);
                int m = m0 + row, b = m >> 11, sp = m & 2047;
                *(bf16x8*)(dst + ((size_t)(b * 16 + hh) * 2048 + sp) * 64 + (chunk & 7) * 8) = v;
            }
        } else {
            // V path: transposed store V^T[b,h,hd,sc]
            const int b = m0 >> 11, h = ((n0 - 1024) >> 6) + wc;
            const int sp = (m0 & 2047) + wr * 64 + quad * 4;
            #pragma unroll
            for (int rt = 0; rt < 4; rt++)
                #pragma unroll
                for (int ct = 0; ct < 4; ct++) {
                    short4 pk;
                    pk.x = f2s(acc[rt][ct][0]); pk.y = f2s(acc[rt][ct][1]);
                    pk.z = f2s(acc[rt][ct][2]); pk.w = f2s(acc[rt][ct][3]);
                    int hd = ct * 16 + l15;
                    *(short4*)(outV + ((size_t)(b * 16 + h) * 64 + hd) * 2048 + sp + rt * 16) = pk;
                }
        }
    } else {
        #pragma unroll
        for (int rt = 0; rt < 4; rt++)
            #pragma unroll
            for (int i = 0; i < 4; i++) {
                size_t m = m0 + wr * 64 + rt * 16 + quad * 4 + i;
                #pragma unroll
                for (int ct = 0; ct < 4; ct++) {
                    int n = n0 + wc * 64 + ct * 16 + l15;
                    outF[m * 1024 + n] = acc[rt][ct][i] + bias_vec[n];
                }
            }
    }
}

// ---------------- attention: 8-wave blocks, 1 q-group/wave, 16 waves/CU ----------------
// S^T = K.Q^T with Q pre-scaled by 0.125*log2e -> p = exp2(st) (row offset
// dropped; cancels in normalization). grid (64,8), 512 threads: block covers
// 256 q-rows (wave w -> rows qt*256 + w*32). Waves 0-3 stage K, 4-7 stage V.
// LDS: K 2buf (16KB) | V 2buf (16KB) | P 8x(32x72) (36KB) = 68KB -> 2 blk/CU.
__global__ __launch_bounds__(512, 4) void attn_kernel(
    const short* __restrict__ Q,   // [64][2048][64]
    const short* __restrict__ K,   // [64][2048][64]
    const short* __restrict__ V,   // [64][64][2048]  (V^T)
    short* __restrict__ AO) {      // [8192][1024] bf16
    __shared__ short smem[8192 + 8192 + 8 * 32 * 72];
    const int tid = threadIdx.x;
    const int w = tid >> 6, lane = tid & 63, quad = lane >> 4, l15 = lane & 15;
    const int bh = blockIdx.x, qt = blockIdx.y;  // grid (64,8): head -> XCD = bh%8
    const short* Qb = Q + (size_t)bh * 2048 * 64;
    const short* Kb = K + (size_t)bh * 2048 * 64;
    const short* Vb = V + (size_t)bh * 64 * 2048;
    short* Pw = smem + 16384 + w * 2304;
    const int q0 = qt * 256 + w * 32;

    // staging role: waves 0-3 stage K tile rows, waves 4-7 stage V^T tile rows
    const int srow = lane >> 2, slot = lane & 3;
    const int sw = (slot ^ ((srow >> 1) & 3)) * 8;
    const int ws = w & 3;
    const bool kstager = (w < 4);
    const short* Sg = kstager ? (Kb + (size_t)(ws * 16 + srow) * 64 + sw)
                              : (Vb + (size_t)(ws * 16 + srow) * 2048 + sw);
    short* Sl0 = smem + (kstager ? 0 : 8192) + ws * 512;
    const int sstep = kstager ? 4096 : 64;  // shorts per kv-tile advance

    bf16x8 bq[2][2];  // [nt][ks]: Q as B-operand B[n=qrow][k=hd]
    #pragma unroll
    for (int nt = 0; nt < 2; nt++)
        #pragma unroll
        for (int ks = 0; ks < 2; ks++)
            bq[nt][ks] = *(const bf16x8*)(Qb + (size_t)(q0 + nt * 16 + l15) * 64 + ks * 32 + quad * 8);

    f32x4 acco[4][2];  // [ct(hd)][nt(qrow)] O^T
    #pragma unroll
    for (int ct = 0; ct < 4; ct++)
        #pragma unroll
        for (int nt = 0; nt < 2; nt++) acco[ct][nt] = f32x4{0.f, 0.f, 0.f, 0.f};
    float lsum[2] = {0.f, 0.f};
    const int rsw = (l15 >> 1) & 3;
    const int rch = (quad ^ rsw) * 8;

    gload16(Sl0,        Sg);
    gload16(Sl0 + 2048, Sg + 32);
    drain_barrier();

    #pragma unroll 1
    for (int t = 0; t < 32; t++) {
        const int cur = (t & 1) * 4096;
        if (t < 31) {
            const int nxt = 4096 - cur;
            gload16(Sl0 + nxt,        Sg + (t + 1) * sstep);
            gload16(Sl0 + nxt + 2048, Sg + (t + 1) * sstep + 32);
        }
        // ---- K fragments, QK^T + exp2 + P stores ----
        bf16x8 ak[4][2];
        #pragma unroll
        for (int mt = 0; mt < 4; mt++)
            #pragma unroll
            for (int ks = 0; ks < 2; ks++)
                ak[mt][ks] = *(const bf16x8*)(smem + cur + ks * 2048 + (mt * 16 + l15) * 32 + rch);

        #pragma unroll
        for (int mt = 0; mt < 4; mt++) {
            #pragma unroll
            for (int nt = 0; nt < 2; nt++) {
                f32x4 st = f32x4{0.f, 0.f, 0.f, 0.f};
                st = mfma16(ak[mt][0], bq[nt][0], st);
                st = mfma16(ak[mt][1], bq[nt][1], st);
                float e0 = __builtin_amdgcn_exp2f(st[0]);
                float e1 = __builtin_amdgcn_exp2f(st[1]);
                float e2 = __builtin_amdgcn_exp2f(st[2]);
                float e3 = __builtin_amdgcn_exp2f(st[3]);
                lsum[nt] += (e0 + e1) + (e2 + e3);
                unsigned int p01 = __builtin_amdgcn_perm(fbits(e1), fbits(e0), 0x07060302u);
                unsigned int p23 = __builtin_amdgcn_perm(fbits(e3), fbits(e2), 0x07060302u);
                uint2 pw;
                pw.x = p01; pw.y = p23;
                *(uint2*)(Pw + (nt * 16 + l15) * 72 + mt * 16 + quad * 4) = pw;
            }
        }
        // P written via uint2*, read via bf16x8*: fence pins program order
        // (wave-local LDS ops execute in issue order -> order == correctness).
        asm volatile("" ::: "memory");

        // ---- V fragments, P reads + PV ----
        bf16x8 av[4][2];
        #pragma unroll
        for (int ct = 0; ct < 4; ct++)
            #pragma unroll
            for (int ks = 0; ks < 2; ks++)
                av[ct][ks] = *(const bf16x8*)(smem + 8192 + cur + ks * 2048 + (ct * 16 + l15) * 32 + rch);

        bf16x8 bp[2][2];
        #pragma unroll
        for (int nt = 0; nt < 2; nt++)
            #pragma unroll
            for (int ks = 0; ks < 2; ks++)
                bp[nt][ks] = *(const bf16x8*)(Pw + (nt * 16 + l15) * 72 + ks * 32 + quad * 8);
        #pragma unroll
        for (int ct = 0; ct < 4; ct++)
            #pragma unroll
            for (int nt = 0; nt < 2; nt++)
                #pragma unroll
                for (int ks = 0; ks < 2; ks++)
                    acco[ct][nt] = mfma16(av[ct][ks], bp[nt][ks], acco[ct][nt]);
        drain_barrier();
    }

    #pragma unroll
    for (int nt = 0; nt < 2; nt++) {
        lsum[nt] += __shfl_xor(lsum[nt], 16, 64);
        lsum[nt] += __shfl_xor(lsum[nt], 32, 64);
    }
    const int b = bh >> 4, h = bh & 15;
    #pragma unroll
    for (int nt = 0; nt < 2; nt++) {
        float inv = 1.f / lsum[nt];
        int sq = q0 + nt * 16 + l15;
        #pragma unroll
        for (int ct = 0; ct < 4; ct++) {
            short4 pk;
            pk.x = f2s(acco[ct][nt][0] * inv); pk.y = f2s(acco[ct][nt][1] * inv);
            pk.z = f2s(acco[ct][nt][2] * inv); pk.w = f2s(acco[ct][nt][3] * inv);
            *(short4*)(AO + ((size_t)b * 2048 + sq) * 1024 + h * 64 + ct * 16 + quad * 4) = pk;
        }
    }
}

extern "C" void kernel_launch(void* const* d_in, const int* in_sizes, int n_in,
                              void* d_out, int out_size, void* d_ws, size_t ws_size,
                              hipStream_t stream) {
    (void)in_sizes; (void)n_in; (void)out_size; (void)ws_size;
    const float* x      = (const float*)d_in[0];
    const float* ctx    = (const float*)d_in[1];
    const float* q_w    = (const float*)d_in[2];
    const float* kv_w   = (const float*)d_in[3];
    const float* qn_s   = (const float*)d_in[4];
    const float* qn_b   = (const float*)d_in[5];
    const float* kn_s   = (const float*)d_in[6];
    const float* kn_b   = (const float*)d_in[7];
    const float* proj_w = (const float*)d_in[8];
    const float* proj_b = (const float*)d_in[9];
    float* out = (float*)d_out;

    char* ws = (char*)d_ws;
    const size_t MB = 1024 * 1024;
    short* xb   = (short*)(ws + 0 * MB);
    short* cb   = (short*)(ws + 16 * MB);
    short* Qb   = (short*)(ws + 32 * MB);   // [64][2048][64] post LN+RoPE+scale
    short* Kb   = (short*)(ws + 48 * MB);   // [64][2048][64] post LN
    short* Vt   = (short*)(ws + 64 * MB);   // [64][64][2048]
    short* AO   = (short*)(ws + 80 * MB);   // [8192][1024]
    short* WqT  = (short*)(ws + 96 * MB);   // 2MB
    short* WkvT = (short*)(ws + 98 * MB);   // 4MB  [2048][1024]
    short* WpT  = (short*)(ws + 102 * MB);  // 2MB

    conv_to_bf16<<<16384, 256, 0, stream>>>(x, ctx, xb, cb);
    transpose_weights<<<dim3(32, 32, 4), 256, 0, stream>>>(q_w, kv_w, proj_w, WqT, WkvT, WpT);
    gemm128<3><<<dim3(64, 24), 256, 0, stream>>>(xb, WqT, cb, WkvT, qn_s, qn_b, kn_s, kn_b,
                                                 Qb, Kb, Vt, nullptr, nullptr);
    attn_kernel<<<dim3(64, 8), 512, 0, stream>>>(Qb, Kb, Vt, AO);
    gemm128<2><<<dim3(64, 8), 256, 0, stream>>>(AO, WpT, nullptr, nullptr, nullptr, nullptr,
                                                nullptr, nullptr, nullptr, nullptr, nullptr,
                                                out, proj_b);
}